// Round 7
// baseline (114.368 us; speedup 1.0000x reference)
//
#include <hip/hip_runtime.h>
#include <hip/hip_bf16.h>
#include <stdint.h>

#define AS1 __attribute__((address_space(1)))
#define AS3 __attribute__((address_space(3)))

typedef __attribute__((ext_vector_type(8))) short bf16x8_t;
typedef __attribute__((ext_vector_type(4))) float f32x4_t;

#define DDIM 1024
#define WT_ELEMS ((size_t)DDIM * DDIM)   // 1 Mi bf16 = 2 MiB
#define XB_ELEMS ((size_t)8192 * DDIM)   // 8 Mi bf16 = 16 MiB

// fp32 -> bf16 round-to-nearest-even (truncation bias over K=1024 would eat
// most of the 0.165 absmax budget).
static __device__ inline ushort f32_to_bf16_rne(float f) {
  union { float f; uint32_t u; } v;
  v.f = f;
  v.u += 0x7FFFu + ((v.u >> 16) & 1u);
  return (ushort)(v.u >> 16);
}

// ---------------------------------------------------------------------------
// Fused one-time prep (single dispatch):
//   blocks [0, nconv):         Xb = bf16(X)               (8 floats/thread)
//   blocks [nconv, nconv+256): Wt[n][k] = bf16(W[k][n])   (64x64 LDS tiles)
// ---------------------------------------------------------------------------
__global__ __launch_bounds__(256) void prep(const float* __restrict__ X,
                                            const float* __restrict__ W,
                                            ushort* __restrict__ Xb,
                                            ushort* __restrict__ Wt,
                                            int nconv) {
  __shared__ float tile[64][65];
  const int t = threadIdx.x;
  if ((int)blockIdx.x < nconv) {
    const size_t i = ((size_t)blockIdx.x * 256 + t) << 3;
    const float4 v0 = *(const float4*)(X + i);
    const float4 v1 = *(const float4*)(X + i + 4);
    union { ushort h[8]; uint4 u; } o;
    o.h[0] = f32_to_bf16_rne(v0.x); o.h[1] = f32_to_bf16_rne(v0.y);
    o.h[2] = f32_to_bf16_rne(v0.z); o.h[3] = f32_to_bf16_rne(v0.w);
    o.h[4] = f32_to_bf16_rne(v1.x); o.h[5] = f32_to_bf16_rne(v1.y);
    o.h[6] = f32_to_bf16_rne(v1.z); o.h[7] = f32_to_bf16_rne(v1.w);
    *(uint4*)(Xb + i) = o.u;
    return;
  }
  const int bid = (int)blockIdx.x - nconv;
  const int bk = bid & 15;   // k-tile of W
  const int bn = bid >> 4;   // n-tile of W
#pragma unroll
  for (int s = 0; s < 4; ++s) {
    const int slot = (s << 8) + t;
    const int r    = slot >> 4;
    const int c4   = (slot & 15) << 2;
    const float4 v = *(const float4*)(W + (size_t)(bk * 64 + r) * DDIM + bn * 64 + c4);
    tile[r][c4 + 0] = v.x; tile[r][c4 + 1] = v.y;
    tile[r][c4 + 2] = v.z; tile[r][c4 + 3] = v.w;
  }
  __syncthreads();
#pragma unroll
  for (int s = 0; s < 2; ++s) {
    const int slot = (s << 8) + t;
    const int n    = slot >> 3;
    const int k8   = (slot & 7) << 3;
    union { ushort h[8]; uint4 u; } tmp;
#pragma unroll
    for (int j = 0; j < 8; ++j) tmp.h[j] = f32_to_bf16_rne(tile[k8 + j][n]);
    *(uint4*)(Wt + (size_t)(bn * 64 + n) * DDIM + bk * 64 + k8) = tmp.u;
  }
}

// ---------------------------------------------------------------------------
// Main GEMM: C[fp32 8192x1024] = Xb * Wt^T.
// R4 shape + R5 double-buffer (R6 fixed: buffer stride is p<<14 = 16384 B,
// the size of one As/Bs buffer; R6's p<<15 wrote A into Bs and B past the
// LDS allocation -> NaN):
//   512 threads (8 waves, 2x4 -> 64x32 wave tiles), 128x128 tile, BK=64,
//   LDS 2 x (16+16) KB = 64 KB -> 2 blocks/CU = 16 waves/CU.
// Per iter: issue tile i+1 into buf p^1, compute tile i, barrier. 16 waves'
// compute + cross-block skew cover the vmcnt(0) drain latency; staging
// L2-BW floor ~1170 cyc/CU/iter.
// Chunk-XOR swizzle (c ^= row&7) on 128-B rows: 0 bank conflicts (measured
// R4) while satisfying global_load_lds' wave-uniform-base + lane*16 layout.
// ---------------------------------------------------------------------------
__global__ __launch_bounds__(512, 2) void gemm_bb(const ushort* __restrict__ Xb,
                                                  const ushort* __restrict__ Wt,
                                                  float* __restrict__ C) {
  __shared__ __align__(16) ushort As[2][128 * 64];  // 2 x 16384 B
  __shared__ __align__(16) ushort Bs[2][128 * 64];  // 2 x 16384 B

  const int t    = threadIdx.x;
  const int wave = t >> 6;
  const int lane = t & 63;
  const int m0 = blockIdx.x * 128;
  const int n0 = blockIdx.y * 128;

  // Staging: thread t covers row sr = t>>3 (0..63) of each 64-row half,
  // swizzled 16B-chunk sc = (t&7)^(sr&7) of the 128-B row. Thread t's LDS
  // slot within a half = wave*1024 + lane*16 = t*16 (identity).
  const int sr = t >> 3;
  const int sc = (t & 7) ^ (sr & 7);
  const ushort* aB = Xb + (size_t)(m0 + sr) * DDIM + (sc << 3);
  const ushort* bB = Wt + (size_t)(n0 + sr) * DDIM + (sc << 3);

  AS3 char* lA = (AS3 char*)&As[0][0];
  AS3 char* lB = (AS3 char*)&Bs[0][0];
  const int woff = wave << 10;

  // Wave tile: 64 rows x 32 cols (4x2 frags of 16x16x32); waves 2(m) x 4(n).
  const int wrr = (wave >> 2) << 6;  // 0 or 64   (m)
  const int wcc = (wave & 3) << 5;   // 0,32,64,96 (n)
  const int fr = lane & 15;
  const int fq = lane >> 4;

  f32x4_t acc[4][2] = {};

  auto issue = [&](int kt, int p) {
    const ushort* a = aB + kt;
    const ushort* b = bB + kt;
    AS3 char* dA = lA + (p << 14) + woff;   // buffer stride = 16384 B
    AS3 char* dB = lB + (p << 14) + woff;
#pragma unroll
    for (int j = 0; j < 2; ++j) {           // halves: rows 0..63 / 64..127
      __builtin_amdgcn_global_load_lds((const AS1 void*)(a + (size_t)(j << 6) * DDIM),
                                       (AS3 void*)(dA + (j << 13)), 16, 0, 0);
      __builtin_amdgcn_global_load_lds((const AS1 void*)(b + (size_t)(j << 6) * DDIM),
                                       (AS3 void*)(dB + (j << 13)), 16, 0, 0);
    }
  };

  issue(0, 0);
  __syncthreads();  // buf0 ready

  for (int i = 0; i < 16; ++i) {
    const int p = i & 1;
    if (i < 15) issue((i + 1) << 6, p ^ 1);  // prefetch next tile, other buffer

    const ushort* Ab = &As[p][0];
    const ushort* Bb = &Bs[p][0];
#pragma unroll
    for (int ks = 0; ks < 2; ++ks) {
      const int kc = (ks << 2) + fq;  // logical 16B-chunk 0..7
      bf16x8_t af[4], bfr[2];
#pragma unroll
      for (int mi = 0; mi < 4; ++mi) {
        const int r = wrr + (mi << 4) + fr;
        af[mi] = *(const bf16x8_t*)&Ab[(r << 6) + ((kc ^ (r & 7)) << 3)];
      }
#pragma unroll
      for (int ni = 0; ni < 2; ++ni) {
        const int r = wcc + (ni << 4) + fr;
        bfr[ni] = *(const bf16x8_t*)&Bb[(r << 6) + ((kc ^ (r & 7)) << 3)];
      }
#pragma unroll
      for (int mi = 0; mi < 4; ++mi)
#pragma unroll
        for (int ni = 0; ni < 2; ++ni)
          acc[mi][ni] = __builtin_amdgcn_mfma_f32_16x16x32_bf16(af[mi], bfr[ni], acc[mi][ni], 0, 0, 0);
    }
    __syncthreads();  // buf p reads done; prefetch drained -> buf p^1 full
  }

  // Epilogue. C/D layout: col = lane&15, row = (lane>>4)*4 + reg.
#pragma unroll
  for (int mi = 0; mi < 4; ++mi) {
#pragma unroll
    for (int r = 0; r < 4; ++r) {
      const int row = m0 + wrr + (mi << 4) + (fq << 2) + r;
      float* crow = C + (size_t)row * DDIM + n0 + wcc + fr;
      crow[0]  = acc[mi][0][r];
      crow[16] = acc[mi][1][r];
    }
  }
}

// ---------------------------------------------------------------------------
// Fallback GEMM (round-2, known correct) if ws can't hold Wt + Xb.
// ---------------------------------------------------------------------------
__global__ __launch_bounds__(256) void gemm_xw(const float* __restrict__ X,
                                               const ushort* __restrict__ Wt,
                                               float* __restrict__ C) {
  __shared__ __align__(16) ushort As[128 * 32];
  __shared__ __align__(16) ushort Bs[128 * 32];
  const int t    = threadIdx.x;
  const int wave = t >> 6;
  const int lane = t & 63;
  const int m0 = blockIdx.x * 128;
  const int n0 = blockIdx.y * 128;
  const int srow  = (wave << 4) + (lane >> 2);
  const int skcol = (lane & 3) << 3;
  const ushort* bptr0 = Wt + (size_t)(n0 + srow) * DDIM + skcol;
  const ushort* bptr1 = Wt + (size_t)(n0 + 64 + srow) * DDIM + skcol;
  const int ar = t >> 2;
  const int ak = (t & 3) << 3;
  const float* aptr0 = X + (size_t)(m0 + ar) * DDIM + ak;
  const float* aptr1 = X + (size_t)(m0 + 64 + ar) * DDIM + ak;
  ushort* asw0 = &As[(ar << 5) + ak];
  ushort* asw1 = &As[((ar + 64) << 5) + ak];
  const int wr = (wave >> 1) << 6;
  const int wc = (wave & 1) << 6;
  const int fr = lane & 15;
  const int fq = lane >> 4;
  f32x4_t acc[4][4] = {};
  AS3 char* ldsB = (AS3 char*)Bs;
  const int woff = wave << 10;
  for (int kt = 0; kt < DDIM; kt += 32) {
    const float4 a00 = *(const float4*)(aptr0);
    const float4 a01 = *(const float4*)(aptr0 + 4);
    const float4 a10 = *(const float4*)(aptr1);
    const float4 a11 = *(const float4*)(aptr1 + 4);
    aptr0 += 32; aptr1 += 32;
    __syncthreads();
    __builtin_amdgcn_global_load_lds((const AS1 void*)bptr0, (AS3 void*)(ldsB + woff),        16, 0, 0);
    __builtin_amdgcn_global_load_lds((const AS1 void*)bptr1, (AS3 void*)(ldsB + 4096 + woff), 16, 0, 0);
    bptr0 += 32; bptr1 += 32;
    union { ushort h[8]; bf16x8_t v; } c0, c1;
    c0.h[0] = f32_to_bf16_rne(a00.x); c0.h[1] = f32_to_bf16_rne(a00.y);
    c0.h[2] = f32_to_bf16_rne(a00.z); c0.h[3] = f32_to_bf16_rne(a00.w);
    c0.h[4] = f32_to_bf16_rne(a01.x); c0.h[5] = f32_to_bf16_rne(a01.y);
    c0.h[6] = f32_to_bf16_rne(a01.z); c0.h[7] = f32_to_bf16_rne(a01.w);
    c1.h[0] = f32_to_bf16_rne(a10.x); c1.h[1] = f32_to_bf16_rne(a10.y);
    c1.h[2] = f32_to_bf16_rne(a10.z); c1.h[3] = f32_to_bf16_rne(a10.w);
    c1.h[4] = f32_to_bf16_rne(a11.x); c1.h[5] = f32_to_bf16_rne(a11.y);
    c1.h[6] = f32_to_bf16_rne(a11.z); c1.h[7] = f32_to_bf16_rne(a11.w);
    *(bf16x8_t*)asw0 = c0.v;
    *(bf16x8_t*)asw1 = c1.v;
    __syncthreads();
    bf16x8_t af[4], bfr[4];
#pragma unroll
    for (int mi = 0; mi < 4; ++mi)
      af[mi] = *(const bf16x8_t*)&As[((wr + (mi << 4) + fr) << 5) + (fq << 3)];
#pragma unroll
    for (int ni = 0; ni < 4; ++ni)
      bfr[ni] = *(const bf16x8_t*)&Bs[((wc + (ni << 4) + fr) << 5) + (fq << 3)];
#pragma unroll
    for (int mi = 0; mi < 4; ++mi)
#pragma unroll
      for (int ni = 0; ni < 4; ++ni)
        acc[mi][ni] = __builtin_amdgcn_mfma_f32_16x16x32_bf16(af[mi], bfr[ni], acc[mi][ni], 0, 0, 0);
  }
#pragma unroll
  for (int mi = 0; mi < 4; ++mi)
#pragma unroll
    for (int r = 0; r < 4; ++r) {
      const int row = m0 + wr + (mi << 4) + (fq << 2) + r;
      float* crow = C + (size_t)row * DDIM + n0 + wc + fr;
#pragma unroll
      for (int ni = 0; ni < 4; ++ni)
        crow[ni << 4] = acc[mi][ni][r];
    }
}

// ---------------------------------------------------------------------------
// softmax over the size-1 sequence axis == 1.0 exactly -> out = x @ kernel[2].
// ---------------------------------------------------------------------------
extern "C" void kernel_launch(void* const* d_in, const int* in_sizes, int n_in,
                              void* d_out, int out_size, void* d_ws, size_t ws_size,
                              hipStream_t stream) {
  const float* x    = (const float*)d_in[0];
  const float* kern = (const float*)d_in[1];
  const float* W = kern + (size_t)2 * DDIM * DDIM;  // kernel[2] — V projection
  ushort* Wt = (ushort*)d_ws;
  const int M = in_sizes[0] / DDIM;  // 8192

  if (ws_size >= (WT_ELEMS + XB_ELEMS) * sizeof(ushort)) {
    ushort* Xb = (ushort*)d_ws + WT_ELEMS;
    const int nconv = (int)((size_t)M * DDIM / 8 / 256);  // 4096
    prep<<<nconv + 256, 256, 0, stream>>>(x, W, Xb, Wt, nconv);
    gemm_bb<<<dim3(M / 128, DDIM / 128), 512, 0, stream>>>(Xb, Wt, (float*)d_out);
  } else {
    prep<<<256, 256, 0, stream>>>(x, W, (ushort*)d_ws, Wt, 0);
    gemm_xw<<<dim3(M / 128, DDIM / 128), 256, 0, stream>>>(x, Wt, (float*)d_out);
  }
}